// Round 1
// baseline (1173.184 us; speedup 1.0000x reference)
//
#include <hip/hip_runtime.h>
#include <hip/hip_bf16.h>

#define NPTS    4096
#define NBATCH  16
#define NPOINT  1024
#define NSAMPLE 32

// ---------------- DPP helpers (wave reductions without LDS round-trips) ---
#define ROW_SHR1  0x111
#define ROW_SHR2  0x112
#define ROW_SHR4  0x114
#define ROW_SHR8  0x118
#define ROW_BC15  0x142
#define ROW_BC31  0x143

template<int CTRL>
__device__ __forceinline__ unsigned dpp_mov(unsigned v) {
    // bound_ctrl=true: invalid source lanes produce 0 (safe identity: keys/vals >= 0)
    return (unsigned)__builtin_amdgcn_update_dpp(0, (int)v, CTRL, 0xF, 0xF, true);
}
template<int CTRL>
__device__ __forceinline__ unsigned long long dpp_max64(unsigned long long k) {
    unsigned lo = dpp_mov<CTRL>((unsigned)(k & 0xFFFFFFFFull));
    unsigned hi = dpp_mov<CTRL>((unsigned)(k >> 32));
    unsigned long long t = ((unsigned long long)hi << 32) | (unsigned long long)lo;
    return (t > k) ? t : k;
}
template<int CTRL>
__device__ __forceinline__ float dpp_maxf(float v) {
    unsigned t = dpp_mov<CTRL>(__float_as_uint(v));
    return fmaxf(v, __uint_as_float(t));
}

// ---------------- K1: farthest point sampling --------------------------------
// One block per batch. 512 threads, 8 points/thread in registers, xyz mirrored
// in LDS for centroid lookup. Exact f32 (no fma) distance to match np argmax.
// Argmax key = (dist_bits<<32) | ~idx  -> u64 max == (max dist, min idx on tie).
__global__ __launch_bounds__(512) void fps_kernel(
    const float* __restrict__ xyz, float* __restrict__ newxyz)
{
    const int b    = blockIdx.x;
    const int tid  = threadIdx.x;
    const int lane = tid & 63;
    const int w    = tid >> 6;
    const float* xb = xyz + (size_t)b * 3 * NPTS;

    __shared__ float X[NPTS], Y[NPTS], Z[NPTS];
    __shared__ unsigned long long slots[2][8];

    float px[8], py[8], pz[8], dist[8];
    #pragma unroll
    for (int j = 0; j < 8; ++j) {
        int n = tid + j * 512;
        px[j] = xb[n]; py[j] = xb[NPTS + n]; pz[j] = xb[2*NPTS + n];
        X[n] = px[j];  Y[n] = py[j];         Z[n] = pz[j];
        dist[j] = 1e10f;
    }
    __syncthreads();

    int f = 0;
    if (tid == 0) {
        newxyz[b*3*NPOINT + 0]        = X[0];
        newxyz[b*3*NPOINT + NPOINT]   = Y[0];
        newxyz[b*3*NPOINT + 2*NPOINT] = Z[0];
    }

    for (int i = 1; i < NPOINT; ++i) {
        const float cx = X[f], cy = Y[f], cz = Z[f];
        float bv = -1.0f; int bi = 0;
        #pragma unroll
        for (int j = 0; j < 8; ++j) {
            float dx = px[j] - cx;
            float dy = py[j] - cy;
            float dz = pz[j] - cz;
            // exact f32, no contraction, same assoc as np: (dx*dx+dy*dy)+dz*dz
            float d = __fadd_rn(__fadd_rn(__fmul_rn(dx,dx), __fmul_rn(dy,dy)),
                                __fmul_rn(dz,dz));
            float nd = fminf(dist[j], d);
            dist[j] = nd;
            if (nd > bv) { bv = nd; bi = tid + j*512; }   // strict > : first max wins
        }
        unsigned long long key =
            ((unsigned long long)__float_as_uint(bv) << 32) |
            (unsigned long long)(unsigned)(~bi);
        key = dpp_max64<ROW_SHR1>(key);
        key = dpp_max64<ROW_SHR2>(key);
        key = dpp_max64<ROW_SHR4>(key);
        key = dpp_max64<ROW_SHR8>(key);
        key = dpp_max64<ROW_BC15>(key);
        key = dpp_max64<ROW_BC31>(key);            // lane 63 = wave max
        unsigned rlo = (unsigned)__builtin_amdgcn_readlane((int)(unsigned)(key & 0xFFFFFFFFull), 63);
        unsigned rhi = (unsigned)__builtin_amdgcn_readlane((int)(unsigned)(key >> 32), 63);
        if (lane == 0)
            slots[i & 1][w] = ((unsigned long long)rhi << 32) | (unsigned long long)rlo;
        __syncthreads();
        unsigned long long kk = slots[i & 1][lane & 7];
        kk = dpp_max64<ROW_SHR1>(kk);
        kk = dpp_max64<ROW_SHR2>(kk);
        kk = dpp_max64<ROW_SHR4>(kk);              // lane 7 = max of 8 slots
        unsigned flo = (unsigned)__builtin_amdgcn_readlane((int)(unsigned)(kk & 0xFFFFFFFFull), 7);
        f = (int)(~flo);
        if (tid == 0) {
            newxyz[b*3*NPOINT + i]            = X[f];
            newxyz[b*3*NPOINT + NPOINT + i]   = Y[f];
            newxyz[b*3*NPOINT + 2*NPOINT + i] = Z[f];
        }
    }
}

// ---------------- K2: query_ball_point ---------------------------------------
// One wave per centroid: ordered scan of all 4096 points; ballot + prefix
// popcount emits the first 32 in-radius indices in ascending order; pad with
// the first found index. Exact f32 distances (no fma).
__global__ __launch_bounds__(256) void ball_kernel(
    const float* __restrict__ xyz, const float* __restrict__ newxyz,
    int* __restrict__ ball_idx)
{
    const int gid  = blockIdx.x * 256 + threadIdx.x;
    const int wid  = gid >> 6;                 // 0 .. 16383
    const int lane = threadIdx.x & 63;
    const int b    = wid >> 10;
    const int m    = wid & (NPOINT - 1);
    const float r2 = (float)(0.2 * 0.2);       // matches jnp's f32 cast of python 0.04..

    const float* xb = xyz + (size_t)b * 3 * NPTS;
    const float cx = newxyz[b*3*NPOINT + m];
    const float cy = newxyz[b*3*NPOINT + NPOINT + m];
    const float cz = newxyz[b*3*NPOINT + 2*NPOINT + m];
    int* out = ball_idx + (size_t)wid * NSAMPLE;

    int base = 0, first = 0;
    for (int c0 = 0; c0 < NPTS; c0 += 64) {
        const int n = c0 + lane;
        float dx = xb[n] - cx, dy = xb[NPTS+n] - cy, dz = xb[2*NPTS+n] - cz;
        float d = __fadd_rn(__fadd_rn(__fmul_rn(dx,dx), __fmul_rn(dy,dy)),
                            __fmul_rn(dz,dz));
        bool inb = (d <= r2);
        unsigned long long mask = __ballot(inb);
        if (base == 0 && mask != 0ull) first = c0 + (int)__builtin_ctzll(mask);
        int pos = base + __popcll(mask & ((1ull << lane) - 1ull));
        if (inb && pos < NSAMPLE) out[pos] = n;
        base += __popcll(mask);
        if (base >= NSAMPLE) break;
    }
    if (lane < NSAMPLE && lane >= base) out[lane] = first;  // pad with first index
}

// ---------------- K0: weight prep --------------------------------------------
// Transpose w0,w1 to k-major (so the MLP's per-k weight reads are contiguous
// wave-uniform scalar loads) and fold conv-bias + batchnorm into scale/shift.
__global__ __launch_bounds__(256) void setup_kernel(
    const float* __restrict__ w0, const float* __restrict__ b0,
    const float* __restrict__ g0, const float* __restrict__ be0,
    const float* __restrict__ m0, const float* __restrict__ v0,
    const float* __restrict__ w1, const float* __restrict__ b1,
    const float* __restrict__ g1, const float* __restrict__ be1,
    const float* __restrict__ m1, const float* __restrict__ v1,
    const float* __restrict__ b2, const float* __restrict__ g2,
    const float* __restrict__ be2, const float* __restrict__ m2,
    const float* __restrict__ v2, float* __restrict__ wp)
{
    const int t = threadIdx.x;
    for (int i = t; i < 64*67; i += 256) {
        int o = i / 67, k = i - o*67;
        wp[k*64 + o] = w0[i];                       // w0t [67][64]
    }
    for (int i = t; i < 64*64; i += 256) {
        int o = i >> 6, k = i & 63;
        wp[4288 + k*64 + o] = w1[i];                // w1t [64][64]
    }
    if (t < 64) {
        float s0 = g0[t] / sqrtf(v0[t] + 1e-5f);
        wp[8384 + t] = s0;
        wp[8448 + t] = (b0[t] - m0[t]) * s0 + be0[t];
        float s1 = g1[t] / sqrtf(v1[t] + 1e-5f);
        wp[8512 + t] = s1;
        wp[8576 + t] = (b1[t] - m1[t]) * s1 + be1[t];
    }
    if (t < 128) {
        float s2 = g2[t] / sqrtf(v2[t] + 1e-5f);
        wp[8640 + t] = s2;
        wp[8768 + t] = (b2[t] - m2[t]) * s2 + be2[t];
    }
}

// ---------------- K3: gather + 3-layer MLP + maxpool -------------------------
// One lane per (centroid, sample) column. 64 lanes = 2 centroids x 32 samples.
// All activations in VGPRs; weights via wave-uniform scalar loads; max over
// 32 samples with a 5-step DPP chain; lanes 31/63 store.
__global__ __launch_bounds__(256) void mlp_kernel(
    const float* __restrict__ xyz, const float* __restrict__ points,
    const float* __restrict__ newxyz, const int* __restrict__ ball_idx,
    const float* __restrict__ wp, const float* __restrict__ w2,
    float* __restrict__ out)
{
    const int col = blockIdx.x * 256 + threadIdx.x;   // 0 .. 524287
    const int m   = (col >> 5) & (NPOINT - 1);
    const int b   = col >> 15;
    const int p   = ball_idx[col];

    const float* xb = xyz + (size_t)b * 3 * NPTS;
    float in[67];
    in[0] = xb[p]          - newxyz[b*3*NPOINT + m];
    in[1] = xb[NPTS + p]   - newxyz[b*3*NPOINT + NPOINT + m];
    in[2] = xb[2*NPTS + p] - newxyz[b*3*NPOINT + 2*NPOINT + m];
    const float* pb = points + (size_t)b * 64 * NPTS;
    #pragma unroll
    for (int c = 0; c < 64; ++c) in[3 + c] = pb[c * NPTS + p];

    const float* w0t = wp;
    const float* w1t = wp + 4288;
    const float* sc0 = wp + 8384;
    const float* sh0 = wp + 8448;
    const float* sc1 = wp + 8512;
    const float* sh1 = wp + 8576;
    const float* sc2 = wp + 8640;
    const float* sh2 = wp + 8768;

    float h[64];
    #pragma unroll
    for (int o = 0; o < 64; ++o) h[o] = 0.0f;
    #pragma unroll
    for (int k = 0; k < 67; ++k) {
        const float x = in[k];
        #pragma unroll
        for (int o = 0; o < 64; ++o) h[o] = fmaf(w0t[k*64 + o], x, h[o]);
    }
    #pragma unroll
    for (int o = 0; o < 64; ++o)
        h[o] = fmaxf(fmaf(h[o], sc0[o], sh0[o]), 0.0f);

    float g[64];
    #pragma unroll
    for (int o = 0; o < 64; ++o) g[o] = 0.0f;
    #pragma unroll
    for (int k = 0; k < 64; ++k) {
        const float x = h[k];
        #pragma unroll
        for (int o = 0; o < 64; ++o) g[o] = fmaf(w1t[k*64 + o], x, g[o]);
    }
    #pragma unroll
    for (int o = 0; o < 64; ++o)
        g[o] = fmaxf(fmaf(g[o], sc1[o], sh1[o]), 0.0f);

    float* outb = out + (size_t)b * 128 * NPOINT + m;
    #pragma unroll 2
    for (int o = 0; o < 128; ++o) {
        float acc = 0.0f;
        const float* wr = w2 + o * 64;
        #pragma unroll
        for (int k = 0; k < 64; ++k) acc = fmaf(wr[k], g[k], acc);
        acc = fmaxf(fmaf(acc, sc2[o], sh2[o]), 0.0f);
        acc = dpp_maxf<ROW_SHR1>(acc);
        acc = dpp_maxf<ROW_SHR2>(acc);
        acc = dpp_maxf<ROW_SHR4>(acc);
        acc = dpp_maxf<ROW_SHR8>(acc);
        acc = dpp_maxf<ROW_BC15>(acc);            // lane31 = max(0..31), lane63 = max(32..63)
        if ((threadIdx.x & 31) == 31) outb[o * NPOINT] = acc;
    }
}

// ---------------- launch ------------------------------------------------------
extern "C" void kernel_launch(void* const* d_in, const int* in_sizes, int n_in,
                              void* d_out, int out_size, void* d_ws, size_t ws_size,
                              hipStream_t stream)
{
    const float* xyz    = (const float*)d_in[0];
    const float* points = (const float*)d_in[1];
    const float* w0  = (const float*)d_in[2];
    const float* b0  = (const float*)d_in[3];
    const float* g0  = (const float*)d_in[4];
    const float* be0 = (const float*)d_in[5];
    const float* m0  = (const float*)d_in[6];
    const float* v0  = (const float*)d_in[7];
    const float* w1  = (const float*)d_in[8];
    const float* b1  = (const float*)d_in[9];
    const float* g1  = (const float*)d_in[10];
    const float* be1 = (const float*)d_in[11];
    const float* m1  = (const float*)d_in[12];
    const float* v1  = (const float*)d_in[13];
    const float* w2  = (const float*)d_in[14];
    const float* b2  = (const float*)d_in[15];
    const float* g2  = (const float*)d_in[16];
    const float* be2 = (const float*)d_in[17];
    const float* m2  = (const float*)d_in[18];
    const float* v2  = (const float*)d_in[19];

    float* out0 = (float*)d_out;                       // (16,3,1024)
    float* out1 = out0 + NBATCH * 3 * NPOINT;          // (16,128,1024)

    int*   ball = (int*)d_ws;                          // 16*1024*32 ints = 2 MB
    float* wp   = (float*)((char*)d_ws + (size_t)NBATCH*NPOINT*NSAMPLE*sizeof(int));

    hipLaunchKernelGGL(setup_kernel, dim3(1), dim3(256), 0, stream,
                       w0,b0,g0,be0,m0,v0, w1,b1,g1,be1,m1,v1, b2,g2,be2,m2,v2, wp);
    hipLaunchKernelGGL(fps_kernel,  dim3(NBATCH), dim3(512), 0, stream, xyz, out0);
    hipLaunchKernelGGL(ball_kernel, dim3(NBATCH*NPOINT/4), dim3(256), 0, stream,
                       xyz, out0, ball);
    hipLaunchKernelGGL(mlp_kernel,  dim3(NBATCH*NPOINT*NSAMPLE/256), dim3(256), 0, stream,
                       xyz, points, out0, ball, wp, w2, out1);
}

// Round 2
// 1106.071 us; speedup vs baseline: 1.0607x; 1.0607x over previous
//
#include <hip/hip_runtime.h>
#include <hip/hip_bf16.h>

#define NPTS    4096
#define NBATCH  16
#define NPOINT  1024
#define NSAMPLE 32

// ---------------- DPP helpers (wave reductions without LDS round-trips) ---
#define ROW_SHR1  0x111
#define ROW_SHR2  0x112
#define ROW_SHR4  0x114
#define ROW_SHR8  0x118
#define ROW_BC15  0x142
#define ROW_BC31  0x143

template<int CTRL>
__device__ __forceinline__ unsigned dpp_mov(unsigned v) {
    // bound_ctrl=true: invalid source lanes produce 0 (safe identity: keys/vals >= 0)
    return (unsigned)__builtin_amdgcn_update_dpp(0, (int)v, CTRL, 0xF, 0xF, true);
}
template<int CTRL>
__device__ __forceinline__ unsigned long long dpp_max64(unsigned long long k) {
    unsigned lo = dpp_mov<CTRL>((unsigned)(k & 0xFFFFFFFFull));
    unsigned hi = dpp_mov<CTRL>((unsigned)(k >> 32));
    unsigned long long t = ((unsigned long long)hi << 32) | (unsigned long long)lo;
    return (t > k) ? t : k;
}
template<int CTRL>
__device__ __forceinline__ float dpp_maxf(float v) {
    unsigned t = dpp_mov<CTRL>(__float_as_uint(v));
    return fmaxf(v, __uint_as_float(t));
}

// ---------------- K1: farthest point sampling --------------------------------
// One block per batch, 256 threads (4 waves = 1 wave/SIMD), 16 CONTIGUOUS
// points per thread (idx = tid*16+j) so min-lane == min-index on ties.
// Exact f32 (no fma) distances to match np argmax bit-for-bit.
// Argmax: per-thread (strict >, first max) -> wave max value via 6-step DPP
// -> ballot(bv==wmax) -> first lane -> readlane(idx). Cross-wave: 4 slots,
// u64 key (valbits<<32)|~idx, 2-step DPP max. One barrier/iter (dbuf slots).
__global__ __launch_bounds__(256) void fps_kernel(
    const float* __restrict__ xyz, float* __restrict__ newxyz)
{
    const int b    = blockIdx.x;
    const int tid  = threadIdx.x;
    const int lane = tid & 63;
    const int w    = tid >> 6;
    const float* xb = xyz + (size_t)b * 3 * NPTS;

    __shared__ float4 P[NPTS];                       // x,y,z,pad (64 KiB)
    __shared__ unsigned long long slots[2][4];

    float px[16], py[16], pz[16], dist[16];
    #pragma unroll
    for (int q = 0; q < 4; ++q) {
        const int n4 = tid * 16 + q * 4;
        float4 xs = *(const float4*)(xb + n4);
        float4 ys = *(const float4*)(xb + NPTS + n4);
        float4 zs = *(const float4*)(xb + 2*NPTS + n4);
        px[q*4+0] = xs.x; px[q*4+1] = xs.y; px[q*4+2] = xs.z; px[q*4+3] = xs.w;
        py[q*4+0] = ys.x; py[q*4+1] = ys.y; py[q*4+2] = ys.z; py[q*4+3] = ys.w;
        pz[q*4+0] = zs.x; pz[q*4+1] = zs.y; pz[q*4+2] = zs.z; pz[q*4+3] = zs.w;
        P[n4+0] = make_float4(xs.x, ys.x, zs.x, 0.f);
        P[n4+1] = make_float4(xs.y, ys.y, zs.y, 0.f);
        P[n4+2] = make_float4(xs.z, ys.z, zs.z, 0.f);
        P[n4+3] = make_float4(xs.w, ys.w, zs.w, 0.f);
    }
    #pragma unroll
    for (int j = 0; j < 16; ++j) dist[j] = 1e10f;
    __syncthreads();

    float4 c0 = P[0];
    float cx = c0.x, cy = c0.y, cz = c0.z;
    if (tid == 0) {
        newxyz[b*3*NPOINT + 0]        = cx;
        newxyz[b*3*NPOINT + NPOINT]   = cy;
        newxyz[b*3*NPOINT + 2*NPOINT] = cz;
    }

    for (int i = 1; i < NPOINT; ++i) {
        float bv = -1.0f; int bj = 0;
        #pragma unroll
        for (int j = 0; j < 16; ++j) {
            float dx = px[j] - cx;
            float dy = py[j] - cy;
            float dz = pz[j] - cz;
            // exact f32, no contraction, same assoc as np: (dx*dx+dy*dy)+dz*dz
            float d = __fadd_rn(__fadd_rn(__fmul_rn(dx,dx), __fmul_rn(dy,dy)),
                                __fmul_rn(dz,dz));
            float nd = fminf(dist[j], d);
            dist[j] = nd;
            if (nd > bv) { bv = nd; bj = j; }        // strict > : first max wins
        }
        const int myidx = (tid << 4) | bj;

        // wave max of bv (32-bit, values >= 0 so bound_ctrl-0 is identity-safe)
        float wv = bv;
        wv = dpp_maxf<ROW_SHR1>(wv);
        wv = dpp_maxf<ROW_SHR2>(wv);
        wv = dpp_maxf<ROW_SHR4>(wv);
        wv = dpp_maxf<ROW_SHR8>(wv);
        wv = dpp_maxf<ROW_BC15>(wv);
        wv = dpp_maxf<ROW_BC31>(wv);                 // lane 63 = wave max
        float wmax = __uint_as_float(
            (unsigned)__builtin_amdgcn_readlane((int)__float_as_uint(wv), 63));
        unsigned long long mask = __ballot(bv == wmax);
        int L = (int)__builtin_ctzll(mask);          // first matching lane = min idx
        int widx = __builtin_amdgcn_readlane(myidx, L);

        if (lane == 0)
            slots[i & 1][w] =
                ((unsigned long long)__float_as_uint(wmax) << 32) |
                (unsigned long long)(unsigned)(~widx);
        __syncthreads();

        unsigned long long kk = slots[i & 1][lane & 3];
        kk = dpp_max64<ROW_SHR1>(kk);
        kk = dpp_max64<ROW_SHR2>(kk);                // lane 3 = max of 4 slots
        unsigned flo = (unsigned)__builtin_amdgcn_readlane(
            (int)(unsigned)(kk & 0xFFFFFFFFull), 3);
        const int f = (int)(~flo);

        float4 cc = P[f];                            // single b128 broadcast read
        cx = cc.x; cy = cc.y; cz = cc.z;
        if (tid == 0) {
            newxyz[b*3*NPOINT + i]            = cx;
            newxyz[b*3*NPOINT + NPOINT + i]   = cy;
            newxyz[b*3*NPOINT + 2*NPOINT + i] = cz;
        }
    }
}

// ---------------- K2: query_ball_point ---------------------------------------
// One wave per centroid: ordered scan of all 4096 points; ballot + prefix
// popcount emits the first 32 in-radius indices in ascending order; pad with
// the first found index. Exact f32 distances (no fma).
__global__ __launch_bounds__(256) void ball_kernel(
    const float* __restrict__ xyz, const float* __restrict__ newxyz,
    int* __restrict__ ball_idx)
{
    const int gid  = blockIdx.x * 256 + threadIdx.x;
    const int wid  = gid >> 6;                 // 0 .. 16383
    const int lane = threadIdx.x & 63;
    const int b    = wid >> 10;
    const int m    = wid & (NPOINT - 1);
    const float r2 = (float)(0.2 * 0.2);

    const float* xb = xyz + (size_t)b * 3 * NPTS;
    const float cx = newxyz[b*3*NPOINT + m];
    const float cy = newxyz[b*3*NPOINT + NPOINT + m];
    const float cz = newxyz[b*3*NPOINT + 2*NPOINT + m];
    int* out = ball_idx + (size_t)wid * NSAMPLE;

    int base = 0, first = 0;
    for (int c0 = 0; c0 < NPTS; c0 += 64) {
        const int n = c0 + lane;
        float dx = xb[n] - cx, dy = xb[NPTS+n] - cy, dz = xb[2*NPTS+n] - cz;
        float d = __fadd_rn(__fadd_rn(__fmul_rn(dx,dx), __fmul_rn(dy,dy)),
                            __fmul_rn(dz,dz));
        bool inb = (d <= r2);
        unsigned long long mask = __ballot(inb);
        if (base == 0 && mask != 0ull) first = c0 + (int)__builtin_ctzll(mask);
        int pos = base + __popcll(mask & ((1ull << lane) - 1ull));
        if (inb && pos < NSAMPLE) out[pos] = n;
        base += __popcll(mask);
        if (base >= NSAMPLE) break;
    }
    if (lane < NSAMPLE && lane >= base) out[lane] = first;  // pad with first index
}

// ---------------- K0: weight prep --------------------------------------------
// Transpose w0,w1 to k-major (so the MLP's per-k weight reads are contiguous
// wave-uniform scalar loads) and fold conv-bias + batchnorm into scale/shift.
__global__ __launch_bounds__(256) void setup_kernel(
    const float* __restrict__ w0, const float* __restrict__ b0,
    const float* __restrict__ g0, const float* __restrict__ be0,
    const float* __restrict__ m0, const float* __restrict__ v0,
    const float* __restrict__ w1, const float* __restrict__ b1,
    const float* __restrict__ g1, const float* __restrict__ be1,
    const float* __restrict__ m1, const float* __restrict__ v1,
    const float* __restrict__ b2, const float* __restrict__ g2,
    const float* __restrict__ be2, const float* __restrict__ m2,
    const float* __restrict__ v2, float* __restrict__ wp)
{
    const int t = threadIdx.x;
    for (int i = t; i < 64*67; i += 256) {
        int o = i / 67, k = i - o*67;
        wp[k*64 + o] = w0[i];                       // w0t [67][64]
    }
    for (int i = t; i < 64*64; i += 256) {
        int o = i >> 6, k = i & 63;
        wp[4288 + k*64 + o] = w1[i];                // w1t [64][64]
    }
    if (t < 64) {
        float s0 = g0[t] / sqrtf(v0[t] + 1e-5f);
        wp[8384 + t] = s0;
        wp[8448 + t] = (b0[t] - m0[t]) * s0 + be0[t];
        float s1 = g1[t] / sqrtf(v1[t] + 1e-5f);
        wp[8512 + t] = s1;
        wp[8576 + t] = (b1[t] - m1[t]) * s1 + be1[t];
    }
    if (t < 128) {
        float s2 = g2[t] / sqrtf(v2[t] + 1e-5f);
        wp[8640 + t] = s2;
        wp[8768 + t] = (b2[t] - m2[t]) * s2 + be2[t];
    }
}

// ---------------- K3: gather + 3-layer MLP + maxpool -------------------------
// One lane per (centroid, sample) column. 64 lanes = 2 centroids x 32 samples.
// All activations in VGPRs; weights via wave-uniform scalar loads; max over
// 32 samples with a 5-step DPP chain; lanes 31/63 store.
__global__ __launch_bounds__(256) void mlp_kernel(
    const float* __restrict__ xyz, const float* __restrict__ points,
    const float* __restrict__ newxyz, const int* __restrict__ ball_idx,
    const float* __restrict__ wp, const float* __restrict__ w2,
    float* __restrict__ out)
{
    const int col = blockIdx.x * 256 + threadIdx.x;   // 0 .. 524287
    const int m   = (col >> 5) & (NPOINT - 1);
    const int b   = col >> 15;
    const int p   = ball_idx[col];

    const float* xb = xyz + (size_t)b * 3 * NPTS;
    float in[67];
    in[0] = xb[p]          - newxyz[b*3*NPOINT + m];
    in[1] = xb[NPTS + p]   - newxyz[b*3*NPOINT + NPOINT + m];
    in[2] = xb[2*NPTS + p] - newxyz[b*3*NPOINT + 2*NPOINT + m];
    const float* pb = points + (size_t)b * 64 * NPTS;
    #pragma unroll
    for (int c = 0; c < 64; ++c) in[3 + c] = pb[c * NPTS + p];

    const float* w0t = wp;
    const float* w1t = wp + 4288;
    const float* sc0 = wp + 8384;
    const float* sh0 = wp + 8448;
    const float* sc1 = wp + 8512;
    const float* sh1 = wp + 8576;
    const float* sc2 = wp + 8640;
    const float* sh2 = wp + 8768;

    float h[64];
    #pragma unroll
    for (int o = 0; o < 64; ++o) h[o] = 0.0f;
    #pragma unroll
    for (int k = 0; k < 67; ++k) {
        const float x = in[k];
        #pragma unroll
        for (int o = 0; o < 64; ++o) h[o] = fmaf(w0t[k*64 + o], x, h[o]);
    }
    #pragma unroll
    for (int o = 0; o < 64; ++o)
        h[o] = fmaxf(fmaf(h[o], sc0[o], sh0[o]), 0.0f);

    float g[64];
    #pragma unroll
    for (int o = 0; o < 64; ++o) g[o] = 0.0f;
    #pragma unroll
    for (int k = 0; k < 64; ++k) {
        const float x = h[k];
        #pragma unroll
        for (int o = 0; o < 64; ++o) g[o] = fmaf(w1t[k*64 + o], x, g[o]);
    }
    #pragma unroll
    for (int o = 0; o < 64; ++o)
        g[o] = fmaxf(fmaf(g[o], sc1[o], sh1[o]), 0.0f);

    float* outb = out + (size_t)b * 128 * NPOINT + m;
    #pragma unroll 2
    for (int o = 0; o < 128; ++o) {
        float acc = 0.0f;
        const float* wr = w2 + o * 64;
        #pragma unroll
        for (int k = 0; k < 64; ++k) acc = fmaf(wr[k], g[k], acc);
        acc = fmaxf(fmaf(acc, sc2[o], sh2[o]), 0.0f);
        acc = dpp_maxf<ROW_SHR1>(acc);
        acc = dpp_maxf<ROW_SHR2>(acc);
        acc = dpp_maxf<ROW_SHR4>(acc);
        acc = dpp_maxf<ROW_SHR8>(acc);
        acc = dpp_maxf<ROW_BC15>(acc);            // lane31 = max(0..31), lane63 = max(32..63)
        if ((threadIdx.x & 31) == 31) outb[o * NPOINT] = acc;
    }
}

// ---------------- launch ------------------------------------------------------
extern "C" void kernel_launch(void* const* d_in, const int* in_sizes, int n_in,
                              void* d_out, int out_size, void* d_ws, size_t ws_size,
                              hipStream_t stream)
{
    const float* xyz    = (const float*)d_in[0];
    const float* points = (const float*)d_in[1];
    const float* w0  = (const float*)d_in[2];
    const float* b0  = (const float*)d_in[3];
    const float* g0  = (const float*)d_in[4];
    const float* be0 = (const float*)d_in[5];
    const float* m0  = (const float*)d_in[6];
    const float* v0  = (const float*)d_in[7];
    const float* w1  = (const float*)d_in[8];
    const float* b1  = (const float*)d_in[9];
    const float* g1  = (const float*)d_in[10];
    const float* be1 = (const float*)d_in[11];
    const float* m1  = (const float*)d_in[12];
    const float* v1  = (const float*)d_in[13];
    const float* w2  = (const float*)d_in[14];
    const float* b2  = (const float*)d_in[15];
    const float* g2  = (const float*)d_in[16];
    const float* be2 = (const float*)d_in[17];
    const float* m2  = (const float*)d_in[18];
    const float* v2  = (const float*)d_in[19];

    float* out0 = (float*)d_out;                       // (16,3,1024)
    float* out1 = out0 + NBATCH * 3 * NPOINT;          // (16,128,1024)

    int*   ball = (int*)d_ws;                          // 16*1024*32 ints = 2 MB
    float* wp   = (float*)((char*)d_ws + (size_t)NBATCH*NPOINT*NSAMPLE*sizeof(int));

    hipLaunchKernelGGL(setup_kernel, dim3(1), dim3(256), 0, stream,
                       w0,b0,g0,be0,m0,v0, w1,b1,g1,be1,m1,v1, b2,g2,be2,m2,v2, wp);
    hipLaunchKernelGGL(fps_kernel,  dim3(NBATCH), dim3(256), 0, stream, xyz, out0);
    hipLaunchKernelGGL(ball_kernel, dim3(NBATCH*NPOINT/4), dim3(256), 0, stream,
                       xyz, out0, ball);
    hipLaunchKernelGGL(mlp_kernel,  dim3(NBATCH*NPOINT*NSAMPLE/256), dim3(256), 0, stream,
                       xyz, points, out0, ball, wp, w2, out1);
}